// Round 4
// baseline (148.001 us; speedup 1.0000x reference)
//
#include <hip/hip_runtime.h>
#include <math.h>

#define NN 768
#define CC 256
#define TI 3     // rows per k_prep block (row-triple)
#define RT 12    // rows per k_attn block
#define JC 192   // j columns per k_attn block
#define NJC 4    // j chunks: 4 * 192 = 768
#define PSTR 16  // pet stride (floats) per jx: 12 rows padded to 16 for b128 alignment

__device__ __forceinline__ float leaky(float x) { return x >= 0.0f ? x : 0.2f * x; }

__device__ __forceinline__ float waveMax(float v) {
    #pragma unroll
    for (int o = 32; o > 0; o >>= 1) v = fmaxf(v, __shfl_xor(v, o, 64));
    return v;
}
__device__ __forceinline__ float waveSum(float v) {
    #pragma unroll
    for (int o = 32; o > 0; o >>= 1) v += __shfl_xor(v, o, 64);
    return v;
}

// Kernel 1: f = features @ FC; g[c][j] = w1*f[j][c]+b (transposed);
// D0/D1 = per-row linear-term dots; ut4[triple][c] = {w0*f_r0[c], w0*f_r1[c],
// w0*f_r2[c], 0.4*lin_w[c]} (L1-broadcast operand for k_attn phase 1).
__global__ __launch_bounds__(768) void k_prep(
    const float* __restrict__ features,
    const float* __restrict__ FC,
    const float* __restrict__ fc_w,
    const float* __restrict__ fc_b,
    const float* __restrict__ lin_w,
    float* __restrict__ f,
    float* __restrict__ g,
    float* __restrict__ D0,
    float* __restrict__ D1,
    float4* __restrict__ ut4)
{
    __shared__ float sA[TI * CC];
    __shared__ float sF[TI * CC];
    __shared__ float sredD[12], sredW[12];

    const int t  = threadIdx.x;
    const int r  = t >> 8;
    const int c  = t & 255;
    const int i0 = blockIdx.x * TI;

    sA[r * CC + c] = features[(i0 + r) * CC + c];
    __syncthreads();

    float a = 0.f;
    const float* fcp = FC + c;
    const float* ap  = sA + r * CC;
    #pragma unroll 8
    for (int k = 0; k < CC; ++k)
        a = fmaf(ap[k], fcp[k * CC], a);

    const float w1 = fc_w[1], b = fc_b[0];
    f[(i0 + r) * CC + c] = a;
    g[c * NN + i0 + r]   = fmaf(w1, a, b);
    sF[r * CC + c] = a;

    const float lw = lin_w[c];
    float dv = waveSum(lw * a);
    float wv = waveSum(lw);
    const int wid = t >> 6;
    if ((t & 63) == 0) { sredD[wid] = dv; sredW[wid] = wv; }
    __syncthreads();
    if (t < TI) {
        float D = sredD[t*4] + sredD[t*4+1] + sredD[t*4+2] + sredD[t*4+3];
        float W = sredW[t*4] + sredW[t*4+1] + sredW[t*4+2] + sredW[t*4+3];
        D0[i0 + t] = fc_w[0] * D;
        D1[i0 + t] = fmaf(w1, D, b * W);
    }
    if (t < CC) {
        const float w0 = fc_w[0];
        ut4[blockIdx.x * CC + t] = make_float4(w0 * sF[t],
                                               w0 * sF[CC + t],
                                               w0 * sF[2*CC + t],
                                               0.4f * lin_w[t]);
    }
}

// Kernel 2: split-j partial attention. Block = (12-row i-tile) x (192-j chunk),
// 768 threads. Phase 1: thread (q=t/192 -> rows 3q..3q+2, jj=t%192 -> j).
// Broadcast operands come from global (L1) not LDS - the DS pipe was the
// round-3 bottleneck (12 waves x 12cyc/b128 re-reading identical values).
__global__ __launch_bounds__(768) void k_attn(
    const float* __restrict__ f,      // [N][C]
    const float* __restrict__ g,      // [C][N]
    const float4* __restrict__ ut4,   // [N/3][C]
    const float* __restrict__ D0,     // [N]
    const float* __restrict__ D1,     // [N]
    const float* __restrict__ coords, // [N][3]
    const float* __restrict__ sc_w,
    const float* __restrict__ sc_b,
    const float* __restrict__ lin_w,  // [C+3]
    const float* __restrict__ lin_b,
    float* __restrict__ pet,          // [gridDim][JC][PSTR] exp values
    float* __restrict__ hp,           // [NJC][N][C] partial sums
    float* __restrict__ Mp,           // [N][NJC] partial max
    float* __restrict__ Lp)           // [N][NJC] partial expsum
{
    __shared__ float sredm[12][3];
    __shared__ float sreds[12][3];

    const int t  = threadIdx.x;
    const int it = blockIdx.x >> 2;
    const int jc = blockIdx.x & 3;
    const int i0 = it * RT;
    const int jb = jc * JC;
    const int q  = t / JC;            // 0..3; waves 3q..3q+2
    const int jj = t - q * JC;        // 0..191
    const int j  = jb + jj;
    const int wid  = t >> 6;
    const int lane = t & 63;

    // ---- Phase 1: 0.4*w*|u+g| accumulation over c for own j, 3 rows ----
    float a0 = 0.f, a1 = 0.f, a2 = 0.f;
    const float*  gp = g + j;
    const float4* up = ut4 + (it * 4 + q) * CC;   // wave-uniform addr -> L1 broadcast
    #pragma unroll 8
    for (int c = 0; c < CC; ++c) {
        float  gj = gp[c * NN];       // coalesced (lanes = consecutive j), L2
        float4 u  = up[c];            // same-address b128, L1-resident
        a0 = fmaf(u.w, fabsf(u.x + gj), a0);
        a1 = fmaf(u.w, fabsf(u.y + gj), a1);
        a2 = fmaf(u.w, fabsf(u.z + gj), a2);
    }

    // coord part + 0.6-linear part + outer leaky
    const float sw0 = sc_w[0], sw1 = sc_w[1], sb = sc_b[0], lb = lin_b[0];
    const float lw30 = lin_w[CC], lw31 = lin_w[CC+1], lw32 = lin_w[CC+2];
    const float cj0 = fmaf(sw1, coords[j*3+0], sb);
    const float cj1 = fmaf(sw1, coords[j*3+1], sb);
    const float cj2 = fmaf(sw1, coords[j*3+2], sb);
    const float d1  = D1[j];
    float accs[3] = {a0, a1, a2};
    float scv[3];
    #pragma unroll
    for (int rr = 0; rr < 3; ++rr) {
        const int i = i0 + 3*q + rr;
        float sd = lw30 * leaky(fmaf(sw0, coords[i*3+0], cj0))
                 + lw31 * leaky(fmaf(sw0, coords[i*3+1], cj1))
                 + lw32 * leaky(fmaf(sw0, coords[i*3+2], cj2));
        scv[rr] = leaky(accs[rr] + sd + 0.6f * (D0[i] + d1) + lb);
    }

    // ---- Phase 2: partial softmax over this block's 192 j's ----
    #pragma unroll
    for (int rr = 0; rr < 3; ++rr) {
        float v = waveMax(scv[rr]);
        if (lane == 0) sredm[wid][rr] = v;
    }
    __syncthreads();
    float m[3];
    #pragma unroll
    for (int rr = 0; rr < 3; ++rr)
        m[rr] = fmaxf(fmaxf(sredm[3*q][rr], sredm[3*q+1][rr]), sredm[3*q+2][rr]);

    float* petB = pet + (size_t)blockIdx.x * JC * PSTR;
    float e[3];
    #pragma unroll
    for (int rr = 0; rr < 3; ++rr) {
        e[rr] = __expf(scv[rr] - m[rr]);
        petB[jj * PSTR + 3*q + rr] = e[rr];   // row 3q+rr of block, column jj
        float v = waveSum(e[rr]);
        if (lane == 0) sreds[wid][rr] = v;
    }
    if (jj == 0) {
        #pragma unroll
        for (int rr = 0; rr < 3; ++rr) {
            // sreds written by this thread's own wave group before barrier below
        }
    }
    __syncthreads();   // drains pet stores (vmcnt(0)) + publishes sreds
    if (jj == 0) {
        #pragma unroll
        for (int rr = 0; rr < 3; ++rr) {
            float l = sreds[3*q][rr] + sreds[3*q+1][rr] + sreds[3*q+2][rr];
            Mp[(i0 + 3*q + rr) * NJC + jc] = m[rr];
            Lp[(i0 + 3*q + rr) * NJC + jc] = l;
        }
    }

    // ---- Phase 3: h_part[r][c] = sum_{jx} e_{r,jx} * f_{jb+jx}[c] ----
    // Thread (rg=t>>8 -> rows 4rg..4rg+3, c=t&255). e via one aligned float4
    // L1-broadcast per jx (was 4x ds_read_b32 - the worst DS hot spot).
    const int rg = t >> 8;
    const int c  = t & 255;
    float h0 = 0.f, h1 = 0.f, h2 = 0.f, h3 = 0.f;
    const float* fp = f + jb * CC + c;
    const float* pb = petB + 4 * rg;
    #pragma unroll 4
    for (int jx = 0; jx < JC; ++jx) {
        float  fv = fp[jx * CC];                          // coalesced, L1/L2
        float4 e4 = *(const float4*)(pb + jx * PSTR);     // same-addr b128, L1
        h0 = fmaf(e4.x, fv, h0);
        h1 = fmaf(e4.y, fv, h1);
        h2 = fmaf(e4.z, fv, h2);
        h3 = fmaf(e4.w, fv, h3);
    }
    float* hpp = hp + ((size_t)jc * NN + i0 + 4*rg) * CC + c;
    hpp[0]    = h0;
    hpp[CC]   = h1;
    hpp[2*CC] = h2;
    hpp[3*CC] = h3;
}

// Kernel 3: combine the 4 j-chunk partials per row, normalize, elu.
__global__ __launch_bounds__(256) void k_comb(
    const float* __restrict__ hp,
    const float* __restrict__ Mp,
    const float* __restrict__ Lp,
    float* __restrict__ out)
{
    const int t = threadIdx.x;
    const int i = blockIdx.x;

    float m0 = Mp[i*NJC+0], m1 = Mp[i*NJC+1], m2 = Mp[i*NJC+2], m3 = Mp[i*NJC+3];
    float M  = fmaxf(fmaxf(m0, m1), fmaxf(m2, m3));
    float w0 = __expf(m0 - M), w1 = __expf(m1 - M);
    float w2 = __expf(m2 - M), w3 = __expf(m3 - M);
    float den = w0*Lp[i*NJC+0] + w1*Lp[i*NJC+1] + w2*Lp[i*NJC+2] + w3*Lp[i*NJC+3];
    float inv = 1.0f / den;

    float num = w0 * hp[((size_t)0*NN + i)*CC + t]
              + w1 * hp[((size_t)1*NN + i)*CC + t]
              + w2 * hp[((size_t)2*NN + i)*CC + t]
              + w3 * hp[((size_t)3*NN + i)*CC + t];
    float v = num * inv;
    out[i*CC + t] = (v > 0.f) ? v : (__expf(v) - 1.0f);
}

extern "C" void kernel_launch(void* const* d_in, const int* in_sizes, int n_in,
                              void* d_out, int out_size, void* d_ws, size_t ws_size,
                              hipStream_t stream) {
    const float* features = (const float*)d_in[0];
    const float* coords   = (const float*)d_in[1];
    // d_in[2] = adj, unused by forward
    const float* FC       = (const float*)d_in[3];
    const float* fc_w     = (const float*)d_in[4];
    const float* fc_b     = (const float*)d_in[5];
    const float* sc_w     = (const float*)d_in[6];
    const float* sc_b     = (const float*)d_in[7];
    const float* lin_w    = (const float*)d_in[8];
    const float* lin_b    = (const float*)d_in[9];
    float* out = (float*)d_out;

    float* f   = (float*)d_ws;             // N*C            = 196608
    float* g   = f   + NN*CC;              // C*N            = 196608
    float* D0  = g   + CC*NN;              // N
    float* D1  = D0  + NN;                 // N
    float* Mp  = D1  + NN;                 // N*NJC
    float* Lp  = Mp  + NN*NJC;             // N*NJC
    float* hp  = Lp  + NN*NJC;             // NJC*N*C        = 786432
    float4* ut4 = (float4*)(hp + (size_t)NJC*NN*CC);   // (N/3)*C float4 (16B-aligned)
    float* pet  = (float*)(ut4 + (NN/TI)*CC);          // 256 blocks * JC * PSTR
    // total ws use ~= 8.9 MiB << ws_size

    k_prep<<<NN/TI, 768, 0, stream>>>(features, FC, fc_w, fc_b, lin_w, f, g, D0, D1, ut4);
    k_attn<<<(NN/RT)*NJC, 768, 0, stream>>>(f, g, ut4, D0, D1, coords, sc_w, sc_b,
                                            lin_w, lin_b, pet, hp, Mp, Lp);
    k_comb<<<NN, 256, 0, stream>>>(hp, Mp, Lp, out);
}

// Round 5
// 114.061 us; speedup vs baseline: 1.2976x; 1.2976x over previous
//
#include <hip/hip_runtime.h>
#include <math.h>

#define NN 768
#define CC 256
#define TI 3     // rows per block (both kernels); 768 = 3 * 256 blocks

__device__ __forceinline__ float leaky(float x) { return x >= 0.0f ? x : 0.2f * x; }

__device__ __forceinline__ float waveMax(float v) {
    #pragma unroll
    for (int o = 32; o > 0; o >>= 1) v = fmaxf(v, __shfl_xor(v, o, 64));
    return v;
}
__device__ __forceinline__ float waveSum(float v) {
    #pragma unroll
    for (int o = 32; o > 0; o >>= 1) v += __shfl_xor(v, o, 64);
    return v;
}

// Kernel 1: f = features @ FC; g[c][j] = w1*f[j][c]+b (transposed);
// D0/D1 = per-row linear-term dots; ut4[triple][c] = {w0*f_r0[c], w0*f_r1[c],
// w0*f_r2[c], 0.4*lin_w[c]} — block-uniform operand k_attn reads via s_load.
__global__ __launch_bounds__(768) void k_prep(
    const float* __restrict__ features,
    const float* __restrict__ FC,
    const float* __restrict__ fc_w,
    const float* __restrict__ fc_b,
    const float* __restrict__ lin_w,
    float* __restrict__ f,
    float* __restrict__ g,
    float* __restrict__ D0,
    float* __restrict__ D1,
    float4* __restrict__ ut4)
{
    __shared__ float sA[TI * CC];
    __shared__ float sF[TI * CC];
    __shared__ float sredD[12], sredW[12];

    const int t  = threadIdx.x;
    const int r  = t >> 8;
    const int c  = t & 255;
    const int i0 = blockIdx.x * TI;

    sA[r * CC + c] = features[(i0 + r) * CC + c];
    __syncthreads();

    float a = 0.f;
    const float* fcp = FC + c;
    const float* ap  = sA + r * CC;
    #pragma unroll 8
    for (int k = 0; k < CC; ++k)
        a = fmaf(ap[k], fcp[k * CC], a);

    const float w1 = fc_w[1], b = fc_b[0];
    f[(i0 + r) * CC + c] = a;
    g[c * NN + i0 + r]   = fmaf(w1, a, b);
    sF[r * CC + c] = a;

    const float lw = lin_w[c];
    float dv = waveSum(lw * a);
    float wv = waveSum(lw);
    const int wid = t >> 6;
    if ((t & 63) == 0) { sredD[wid] = dv; sredW[wid] = wv; }
    __syncthreads();
    if (t < TI) {
        float D = sredD[t*4] + sredD[t*4+1] + sredD[t*4+2] + sredD[t*4+3];
        float W = sredW[t*4] + sredW[t*4+1] + sredW[t*4+2] + sredW[t*4+3];
        D0[i0 + t] = fc_w[0] * D;
        D1[i0 + t] = fmaf(w1, D, b * W);
    }
    if (t < CC) {
        const float w0 = fc_w[0];
        ut4[blockIdx.x * CC + t] = make_float4(w0 * sF[t],
                                               w0 * sF[CC + t],
                                               w0 * sF[2*CC + t],
                                               0.4f * lin_w[t]);
    }
}

// Kernel 2: block = 3 rows x all 768 j, 768 threads (12 waves).
// Phase 1: thread t owns j=t; u comes from ut4 via SCALAR loads (block-uniform
// address -> s_load_dwordx4, constant-cache pipe; DS pipe stays idle).
// Phase 3: wave w owns j in [64w,64w+64); lane owns 4 channels (float4 f);
// pp[j] is ONE ds_read_b128 per 768 cells (12x fewer DS than round 2).
__global__ __launch_bounds__(768) void k_attn(
    const float* __restrict__ f,      // [N][C]
    const float* __restrict__ g,      // [C][N]
    const float4* __restrict__ ut4,   // [N/3][C]
    const float* __restrict__ D0,     // [N]
    const float* __restrict__ D1,     // [N]
    const float* __restrict__ coords, // [N][3]
    const float* __restrict__ sc_w,
    const float* __restrict__ sc_b,
    const float* __restrict__ lin_w,  // [C+3]
    const float* __restrict__ lin_b,
    float* __restrict__ out)
{
    __shared__ float4 pp[NN];            // 12 KB: {e0,e1,e2,-} per j
    __shared__ float  hpart[12][TI][CC]; // 36 KB: per-wave h partials
    __shared__ float4 sredm4[12];
    __shared__ float4 sreds4[12];

    const int t    = threadIdx.x;
    const int i0   = blockIdx.x * TI;
    const int w    = t >> 6;
    const int lane = t & 63;

    // ---- Phase 1: 0.4*wc*|u_r + g_j| accumulated over c; j = t ----
    float a0 = 0.f, a1 = 0.f, a2 = 0.f;
    const float*  gp = g + t;
    const float4* up = ut4 + (size_t)blockIdx.x * CC;  // block-uniform -> s_load
    #pragma unroll 8
    for (int c = 0; c < CC; ++c) {
        float  gj = gp[c * NN];       // coalesced 256B/wave, L2
        float4 u  = up[c];            // scalar pipe (SGPRs)
        a0 = fmaf(u.w, fabsf(u.x + gj), a0);
        a1 = fmaf(u.w, fabsf(u.y + gj), a1);
        a2 = fmaf(u.w, fabsf(u.z + gj), a2);
    }

    // coord part + 0.6-linear part + outer leaky
    const float sw0 = sc_w[0], sw1 = sc_w[1], sb = sc_b[0], lb = lin_b[0];
    const float lw30 = lin_w[CC], lw31 = lin_w[CC+1], lw32 = lin_w[CC+2];
    const float cj0 = fmaf(sw1, coords[t*3+0], sb);
    const float cj1 = fmaf(sw1, coords[t*3+1], sb);
    const float cj2 = fmaf(sw1, coords[t*3+2], sb);
    const float d1  = D1[t];
    float accs[3] = {a0, a1, a2};
    float scv[3];
    #pragma unroll
    for (int rr = 0; rr < TI; ++rr) {
        const int i = i0 + rr;
        float sd = lw30 * leaky(fmaf(sw0, coords[i*3+0], cj0))
                 + lw31 * leaky(fmaf(sw0, coords[i*3+1], cj1))
                 + lw32 * leaky(fmaf(sw0, coords[i*3+2], cj2));
        scv[rr] = leaky(accs[rr] + sd + 0.6f * (D0[i] + d1) + lb);
    }

    // ---- Phase 2: block-wide softmax over the 768 j's, 3 rows ----
    {
        float v0 = waveMax(scv[0]);
        float v1 = waveMax(scv[1]);
        float v2 = waveMax(scv[2]);
        if (lane == 0) sredm4[w] = make_float4(v0, v1, v2, 0.f);
    }
    __syncthreads();
    float m[TI];
    {
        float4 mm = sredm4[0];
        #pragma unroll
        for (int ww = 1; ww < 12; ++ww) {
            float4 x = sredm4[ww];
            mm.x = fmaxf(mm.x, x.x); mm.y = fmaxf(mm.y, x.y); mm.z = fmaxf(mm.z, x.z);
        }
        m[0] = mm.x; m[1] = mm.y; m[2] = mm.z;
    }
    float e0 = __expf(scv[0] - m[0]);
    float e1 = __expf(scv[1] - m[1]);
    float e2 = __expf(scv[2] - m[2]);
    pp[t] = make_float4(e0, e1, e2, 0.f);
    {
        float v0 = waveSum(e0);
        float v1 = waveSum(e1);
        float v2 = waveSum(e2);
        if (lane == 0) sreds4[w] = make_float4(v0, v1, v2, 0.f);
    }
    __syncthreads();   // publishes pp + sreds4
    float inv[TI];
    {
        float4 ss = sreds4[0];
        #pragma unroll
        for (int ww = 1; ww < 12; ++ww) {
            float4 x = sreds4[ww];
            ss.x += x.x; ss.y += x.y; ss.z += x.z;
        }
        inv[0] = 1.0f / ss.x; inv[1] = 1.0f / ss.y; inv[2] = 1.0f / ss.z;
    }

    // ---- Phase 3: wave w covers j in [64w, 64w+64); lane owns channels 4*lane.. ----
    float4 h0 = make_float4(0.f,0.f,0.f,0.f);
    float4 h1 = h0, h2 = h0;
    const float4* f4 = (const float4*)f;   // [N][64] float4 rows
    const int jb = w * 64;
    #pragma unroll 4
    for (int jj = 0; jj < 64; ++jj) {
        const int j = jb + jj;
        float4 fv = f4[(size_t)j * 64 + lane];  // coalesced 1KB/wave
        float4 e  = pp[j];                       // one b128 broadcast / 768 cells
        h0.x = fmaf(e.x, fv.x, h0.x); h0.y = fmaf(e.x, fv.y, h0.y);
        h0.z = fmaf(e.x, fv.z, h0.z); h0.w = fmaf(e.x, fv.w, h0.w);
        h1.x = fmaf(e.y, fv.x, h1.x); h1.y = fmaf(e.y, fv.y, h1.y);
        h1.z = fmaf(e.y, fv.z, h1.z); h1.w = fmaf(e.y, fv.w, h1.w);
        h2.x = fmaf(e.z, fv.x, h2.x); h2.y = fmaf(e.z, fv.y, h2.y);
        h2.z = fmaf(e.z, fv.z, h2.z); h2.w = fmaf(e.z, fv.w, h2.w);
    }
    *(float4*)&hpart[w][0][4*lane] = h0;
    *(float4*)&hpart[w][1][4*lane] = h1;
    *(float4*)&hpart[w][2][4*lane] = h2;
    __syncthreads();

    // ---- Reduce 12 wave-partials; normalize; elu; store ----
    {
        const int r = t >> 8;       // 0..2 (uniform per wave)
        const int c = t & 255;
        float h = 0.f;
        #pragma unroll
        for (int ww = 0; ww < 12; ++ww) h += hpart[ww][r][c];
        float v = h * inv[r];
        out[(i0 + r) * CC + c] = (v > 0.f) ? v : (__expf(v) - 1.0f);
    }
}

extern "C" void kernel_launch(void* const* d_in, const int* in_sizes, int n_in,
                              void* d_out, int out_size, void* d_ws, size_t ws_size,
                              hipStream_t stream) {
    const float* features = (const float*)d_in[0];
    const float* coords   = (const float*)d_in[1];
    // d_in[2] = adj, unused by forward
    const float* FC       = (const float*)d_in[3];
    const float* fc_w     = (const float*)d_in[4];
    const float* fc_b     = (const float*)d_in[5];
    const float* sc_w     = (const float*)d_in[6];
    const float* sc_b     = (const float*)d_in[7];
    const float* lin_w    = (const float*)d_in[8];
    const float* lin_b    = (const float*)d_in[9];
    float* out = (float*)d_out;

    float* f   = (float*)d_ws;             // N*C
    float* g   = f   + NN*CC;              // C*N
    float* D0  = g   + CC*NN;              // N
    float* D1  = D0  + NN;                 // N
    float* pad = D1  + NN;                 // align to 16B
    float4* ut4 = (float4*)(pad + (16 - (((size_t)(pad - (float*)d_ws)) & 3)) % 16);
    // simpler: recompute aligned base
    {
        size_t off = (size_t)(D1 + NN) - (size_t)d_ws;
        off = (off + 15) & ~(size_t)15;
        ut4 = (float4*)((char*)d_ws + off);
    }

    k_prep<<<NN/TI, 768, 0, stream>>>(features, FC, fc_w, fc_b, lin_w, f, g, D0, D1, ut4);
    k_attn<<<NN/TI, 768, 0, stream>>>(f, g, ut4, D0, D1, coords, sc_w, sc_b,
                                      lin_w, lin_b, out);
}